// Round 12
// baseline (79.861 us; speedup 1.0000x reference)
//
#include <hip/hip_runtime.h>
#include <stdint.h>

#define Bdim 512
#define Tdim 2000
#define Ddim 20
#define Hdim 128
#define Cdim 10
#define NCH  32              // 31 full 64-t chunks + 16-t tail (chunk 31)
#define BETA 0.95f
#define THR  0.8f

typedef float f32x2 __attribute__((ext_vector_type(2)));
typedef float f32x4 __attribute__((ext_vector_type(4)));
typedef int   i32x4 __attribute__((ext_vector_type(4)));

// f32 pair -> packed bf16 hi + packed bf16 lo (RNE)
#define CVT_HILO(HI, LO, F0, F1) {                                                     \
    asm volatile("v_cvt_pk_bf16_f32 %0, %1, %2" : "=v"(HI) : "v"(F0), "v"(F1));        \
    const float h0f_ = __uint_as_float((HI) << 16);                                    \
    const float h1f_ = __uint_as_float((HI) & 0xFFFF0000u);                            \
    const float l0_ = (F0) - h0f_;  const float l1_ = (F1) - h1f_;                     \
    asm volatile("v_cvt_pk_bf16_f32 %0, %1, %2" : "=v"(LO) : "v"(l0_), "v"(l1_)); }

#define MFMA0(ACC, A8, B8) \
  asm volatile("v_mfma_f32_16x16x32_bf16 %0, %1, %2, 0"  : "=v"(ACC) : "v"(A8), "v"(B8));
#define MFMA(ACC, A8, B8)  \
  asm volatile("v_mfma_f32_16x16x32_bf16 %0, %1, %2, %0" : "+v"(ACC) : "v"(A8), "v"(B8));

__global__ __launch_bounds__(128, 1) void snn_fuse3_kernel(
    const float* __restrict__ x,   // [B,T,D]
    const float* __restrict__ W1,  // [H,D]
    const float* __restrict__ b1,  // [H]
    const float* __restrict__ W2,  // [C,H]
    const float* __restrict__ b2,  // [C]
    float* __restrict__ out)       // [B,C]
{
  const int b   = blockIdx.x;
  const int tid = threadIdx.x;    // 0..127
  const int wid = tid >> 6;       // wave 0: h 0-63, wave 1: h 64-127
  const int l   = tid & 63;
  const int r   = l & 15;
  const int g   = l >> 4;

  __shared__ __align__(16) float xraw[2][1280];        // 10240 B (64 t x 20 d, dbuf)
  __shared__ __align__(16) float cur[2][2][64 * 66];   // 67584 B  [wave][buf], stride 66 dw
  __shared__ float cnt_s[Hdim];

  const float* xb = x + (size_t)b * (Tdim * Ddim);
  const float* const clampMax = x + (size_t)Bdim * Tdim * Ddim - 4;

  const uint32_t xrawB = (uint32_t)(uintptr_t)&xraw[0][0];
  const uint32_t curB  = (uint32_t)(uintptr_t)&cur[0][0][0];

  // ---- B fragments: 4 ni covering this wave's 64 h; bias rider at k=20 ----
  i32x4 bhi[4], blo[4];
  f32x4 zero4, ovr;
  const bool g2 = (g == 2), g3f = (g == 3), sel23 = g2 | g3f;
  zero4[0]=0.f; zero4[1]=0.f; zero4[2]=0.f; zero4[3]=0.f;
  ovr = zero4; if (g2) ovr[0] = 1.0f;
#pragma unroll
  for (int ni = 0; ni < 4; ++ni) {
    const int hh = (wid << 6) + ni * 16 + r;
    float wv[8];
#pragma unroll
    for (int j = 0; j < 8; ++j) {
      const int k = 8 * g + j;
      wv[j] = (k < Ddim) ? W1[hh * Ddim + k] : ((k == Ddim) ? b1[hh] : 0.0f);
    }
#pragma unroll
    for (int d = 0; d < 4; ++d) {
      const uint32_t u0 = __float_as_uint(wv[2*d]), u1 = __float_as_uint(wv[2*d+1]);
      const uint32_t h0 = (u0 + 0x8000u) & 0xFFFF0000u;
      const uint32_t h1 = (u1 + 0x8000u) & 0xFFFF0000u;
      bhi[ni][d] = (int)(h1 | (h0 >> 16));
      const float l0 = wv[2*d]   - __uint_as_float(h0);
      const float l1 = wv[2*d+1] - __uint_as_float(h1);
      const uint32_t e0 = (__float_as_uint(l0) + 0x8000u) & 0xFFFF0000u;
      const uint32_t e1 = (__float_as_uint(l1) + 0x8000u) & 0xFFFF0000u;
      blo[ni][d] = (int)(e1 | (e0 >> 16));
    }
  }

  // ---- scan state ----
  float    mem = 0.0f;
  bool     sp  = false;
  uint32_t cnt = 0u;
  f32x2    negT2; negT2[0] = -THR; negT2[1] = -THR;

  // wave stages its own 32 t-rows (2560 B) of the shared x chunk
#define STAGE(CH, BUF) do {                                                            \
    const float* g0_ = xb + (CH) * 1280 + wid * 640 + l * 4;                           \
    char* lb_ = (char*)&xraw[0][0] + (BUF) * 5120 + wid * 2560 + l * 16;               \
    const float* p0_ = g0_;        if (p0_ > clampMax) p0_ = clampMax;                 \
    const float* p1_ = g0_ + 256;  if (p1_ > clampMax) p1_ = clampMax;                 \
    __builtin_amdgcn_global_load_lds(                                                  \
      (const __attribute__((address_space(1))) unsigned int*)p0_,                      \
      (__attribute__((address_space(3))) unsigned int*)lb_, 16, 0, 0);                 \
    __builtin_amdgcn_global_load_lds(                                                  \
      (const __attribute__((address_space(1))) unsigned int*)p1_,                      \
      (__attribute__((address_space(3))) unsigned int*)(lb_ + 1024), 16, 0, 0);        \
    if (l < 32) {                                                                      \
      const float* p2_ = g0_ + 512;  if (p2_ > clampMax) p2_ = clampMax;               \
      __builtin_amdgcn_global_load_lds(                                                \
        (const __attribute__((address_space(1))) unsigned int*)p2_,                    \
        (__attribute__((address_space(3))) unsigned int*)(lb_ + 2048), 16, 0, 0);      \
    } } while (0)

#define VM0()  asm volatile("s_waitcnt vmcnt(0)" ::: "memory");
#define LGW(N) asm volatile("s_waitcnt lgkmcnt(" #N ")" ::: "memory"); __builtin_amdgcn_sched_barrier(0);
#define BAR()  __builtin_amdgcn_sched_barrier(0); __builtin_amdgcn_s_barrier(); __builtin_amdgcn_sched_barrier(0);

#define CVT8(AHI, ALO, A0, A1) {                                                       \
    uint32_t h_, lo_;                                                                  \
    CVT_HILO(h_, lo_, A0[0], A0[1]) AHI[0]=(int)h_; ALO[0]=(int)lo_;                   \
    CVT_HILO(h_, lo_, A0[2], A0[3]) AHI[1]=(int)h_; ALO[1]=(int)lo_;                   \
    CVT_HILO(h_, lo_, A1[0], A1[1]) AHI[2]=(int)h_; ALO[2]=(int)lo_;                   \
    CVT_HILO(h_, lo_, A1[2], A1[3]) AHI[3]=(int)h_; ALO[3]=(int)lo_; }

  // A-reads: 8 upfront (all 4 tiles), immediate offsets off one base
#define ARD8()                                                                         \
  asm volatile("ds_read_b128 %0, %1 offset:0"    : "=v"(ax00) : "v"(afb));             \
  asm volatile("ds_read_b128 %0, %1 offset:16"   : "=v"(ax01) : "v"(afb));             \
  asm volatile("ds_read_b128 %0, %1 offset:1280" : "=v"(ax10) : "v"(afb));             \
  asm volatile("ds_read_b128 %0, %1 offset:1296" : "=v"(ax11) : "v"(afb));             \
  asm volatile("ds_read_b128 %0, %1 offset:2560" : "=v"(ax20) : "v"(afb));             \
  asm volatile("ds_read_b128 %0, %1 offset:2576" : "=v"(ax21) : "v"(afb));             \
  asm volatile("ds_read_b128 %0, %1 offset:3840" : "=v"(ax30) : "v"(afb));             \
  asm volatile("ds_read_b128 %0, %1 offset:3856" : "=v"(ax31) : "v"(afb));
#define ARD2()                                                                         \
  asm volatile("ds_read_b128 %0, %1 offset:0"    : "=v"(ax00) : "v"(afb));             \
  asm volatile("ds_read_b128 %0, %1 offset:16"   : "=v"(ax01) : "v"(afb));

#define TILE(MT) {                                                                     \
    f32x4 a0_ = ax##MT##0, a1_ = ax##MT##1;                                            \
    a0_ = g3f   ? zero4 : a0_;                                                         \
    a1_ = sel23 ? ovr   : a1_;                                                         \
    i32x4 ahi_, alo_;  CVT8(ahi_, alo_, a0_, a1_)                                      \
    asm volatile("s_nop 2");                                                           \
    MFMA0(c##MT##_0, alo_, bhi[0]) MFMA0(c##MT##_1, alo_, bhi[1])                      \
    MFMA0(c##MT##_2, alo_, bhi[2]) MFMA0(c##MT##_3, alo_, bhi[3])                      \
    MFMA (c##MT##_0, ahi_, blo[0]) MFMA (c##MT##_1, ahi_, blo[1])                      \
    MFMA (c##MT##_2, ahi_, blo[2]) MFMA (c##MT##_3, ahi_, blo[3])                      \
    MFMA (c##MT##_0, ahi_, bhi[0]) MFMA (c##MT##_1, ahi_, bhi[1])                      \
    MFMA (c##MT##_2, ahi_, bhi[2]) MFMA (c##MT##_3, ahi_, bhi[3]) }

  // cur writes: t-major stride 66 dw; per tile 8 write2 (ni-immediate offsets)
#define WT1(CW, ACC, NI)                                                               \
    asm volatile("ds_write2_b32 %0, %1, %2 offset0:%c3 offset1:%c4"                    \
                 :: "v"(CW), "v"(ACC[0]), "v"(ACC[1]), "n"(16*(NI)), "n"(16*(NI)+66)); \
    asm volatile("ds_write2_b32 %0, %1, %2 offset0:%c3 offset1:%c4"                    \
                 :: "v"(CW), "v"(ACC[2]), "v"(ACC[3]), "n"(16*(NI)+132), "n"(16*(NI)+198));
#define WTILE(MT) { const uint32_t cw_ = cwb + (MT) * (16u * 264u);                    \
    WT1(cw_, c##MT##_0, 0) WT1(cw_, c##MT##_1, 1)                                      \
    WT1(cw_, c##MT##_2, 2) WT1(cw_, c##MT##_3, 3) }

  // ---- scan: ring-7 read2, counted lgkm; identical arithmetic to r10 ----
#define RD2A(PR, AD) asm volatile("ds_read2_b32 %0, %1 offset0:0 offset1:66" : "=v"(PR) : "v"(AD));
#define CONSUME(PR) {                                                                  \
    f32x2 cm_; asm("v_pk_add_f32 %0, %1, %2" : "=v"(cm_) : "v"(PR), "v"(negT2));       \
    float mP_ = fmaf(BETA, mem, PR[0]);                                                \
    float mM_ = fmaf(BETA, mem, cm_[0]);                                               \
    mem = sp ? mM_ : mP_;                                                              \
    sp  = mem > THR;                                                                   \
    cnt += sp ? 1u : 0u;                                                               \
    mP_ = fmaf(BETA, mem, PR[1]);                                                      \
    mM_ = fmaf(BETA, mem, cm_[1]);                                                     \
    mem = sp ? mM_ : mP_;                                                              \
    sp  = mem > THR;                                                                   \
    cnt += sp ? 1u : 0u; }
#define SPRE()                                                                         \
    f32x2 pr0, pr1, pr2, pr3, pr4, pr5, pr6;                                           \
    RD2A(pr0, spB)         RD2A(pr1, spB + 528u)  RD2A(pr2, spB + 1056u)               \
    RD2A(pr3, spB + 1584u) RD2A(pr4, spB + 2112u) RD2A(pr5, spB + 2640u)               \
    RD2A(pr6, spB + 3168u)
#define SSX(RG, SLOT) { LGW(6) CONSUME(pr##RG)                                         \
    { const uint32_t ad_ = spB + (uint32_t)((SLOT) * 528u); RD2A(pr##RG, ad_) } }
#define TSX(RG, W)    { LGW(W) CONSUME(pr##RG) }

#define SCAN32_A()  /* c = 0..7  */                                                    \
    SSX(0,7)  SSX(1,8)  SSX(2,9)  SSX(3,10) SSX(4,11) SSX(5,12) SSX(6,13) SSX(0,14)
#define SCAN32_B()  /* c = 8..15 */                                                    \
    SSX(1,15) SSX(2,16) SSX(3,17) SSX(4,18) SSX(5,19) SSX(6,20) SSX(0,21) SSX(1,22)
#define SCAN32_C()  /* c = 16..23 */                                                   \
    SSX(2,23) SSX(3,24) SSX(4,25) SSX(5,26) SSX(6,27) SSX(0,28) SSX(1,29) SSX(2,30)
#define SCAN32_D()  /* c = 24..31 */                                                   \
    SSX(3,31) TSX(4,6) TSX(5,5) TSX(6,4) TSX(0,3) TSX(1,2) TSX(2,1) TSX(3,0)

  const uint32_t afb0 = xrawB + (uint32_t)(80 * r + 32 * g);
  const uint32_t cwb0 = curB + (uint32_t)(wid * 33792 + (4 * g) * 264 + 4 * r);
  const uint32_t spB0 = curB + (uint32_t)(wid * 33792 + 4 * l);

  f32x4 ax00, ax01, ax10, ax11, ax20, ax21, ax30, ax31;
  f32x4 c0_0,c0_1,c0_2,c0_3, c1_0,c1_1,c1_2,c1_3,
        c2_0,c2_1,c2_2,c2_3, c3_0,c3_1,c3_2,c3_3;

  STAGE(0, 0);

  // ---------- ph = 0: GEMM chunk 0 only ----------
  {
    VM0() BAR()
    STAGE(1, 1);
    const uint32_t afb = afb0;            // pbuf 0
    const uint32_t cwb = cwb0;            // pbuf 0
    ARD8() LGW(0)
    TILE(0) TILE(1) TILE(2) TILE(3)
    asm volatile("s_nop 7"); asm volatile("s_nop 4");
    WTILE(0) WTILE(1) WTILE(2) WTILE(3)
    LGW(0)
  }

  // ---------- ph = 1..30: GEMM chunk ph  ||  scan chunk ph-1 ----------
#pragma unroll 1
  for (int ph = 1; ph <= 30; ++ph) {
    VM0() BAR()
    STAGE(ph + 1, (ph + 1) & 1);
    const uint32_t pb  = (uint32_t)(ph & 1);
    const uint32_t afb = afb0 + pb * 5120u;
    const uint32_t cwb = cwb0 + pb * 16896u;
    const uint32_t spB = spB0 + (1u - pb) * 16896u;
    ARD8() SPRE()
    LGW(7)
    TILE(0) SCAN32_A()
    TILE(1) SCAN32_B()
    TILE(2) SCAN32_C()
    TILE(3) SCAN32_D()
    WTILE(0) WTILE(1) WTILE(2) WTILE(3)
    LGW(0)
  }

  // ---------- ph = 31: tail GEMM (chunk 31 = 16 t)  ||  scan chunk 30 ----------
  {
    VM0() BAR()
    const uint32_t afb = afb0 + 5120u;    // pbuf 1
    const uint32_t cwb = cwb0 + 16896u;   // pbuf 1
    const uint32_t spB = spB0;            // buf 0 (chunk 30)
    ARD2() SPRE()
    LGW(7)
    TILE(0)
    SCAN32_A() SCAN32_B() SCAN32_C() SCAN32_D()
    WTILE(0)
    LGW(0)
  }

  // ---------- ph = 32: scan chunk 31 (16 t = 8 slots) ----------
  {
    const uint32_t spB = spB0 + 16896u;   // buf 1
    SPRE()
    SSX(0,7)
    TSX(1,6) TSX(2,5) TSX(3,4) TSX(4,3) TSX(5,2) TSX(6,1) TSX(0,0)
  }

  cnt_s[(wid << 6) + l] = (float)cnt;
  __syncthreads();

  // ---- fused epilogue: logits from spike counts ----
  if (tid < Cdim) {
    float dot = 0.0f;
#pragma unroll
    for (int k = 0; k < Hdim; ++k)
      dot = fmaf(cnt_s[k], W2[tid * Hdim + k], dot);
    const float Tf = (float)Tdim;
    const float scale = 1.0f / Tf + 0.1f / (Tf + 1e-6f);
    out[b * Cdim + tid] = fmaf(dot, scale, 1.1f * b2[tid]);
  }
}

extern "C" void kernel_launch(void* const* d_in, const int* in_sizes, int n_in,
                              void* d_out, int out_size, void* d_ws, size_t ws_size,
                              hipStream_t stream) {
  const float* x  = (const float*)d_in[0];
  const float* W1 = (const float*)d_in[1];
  const float* b1 = (const float*)d_in[2];
  const float* W2 = (const float*)d_in[3];
  const float* b2 = (const float*)d_in[4];
  float* out = (float*)d_out;

  snn_fuse3_kernel<<<dim3(Bdim), dim3(128), 0, stream>>>(x, W1, b1, W2, b2, out);
}